// Round 5
// baseline (518.464 us; speedup 1.0000x reference)
//
#include <hip/hip_runtime.h>
#include <hip/hip_bf16.h>

typedef __attribute__((ext_vector_type(8))) short short8;
typedef __attribute__((ext_vector_type(4))) float floatx4;

#define DEVI __device__ __forceinline__

// ---------------- constants ----------------
// B=4, N=512, C_IN=256, RES=7, SR=2, FC_DIM=1024, OUT_CH=94
// M = B*N = 2048 rows, K1 = 256*7*7 = 12544

DEVI unsigned short f2bf(float v) {
  union { __hip_bfloat16 h; unsigned short u; } cv;
  cv.h = __float2bfloat16(v);
  return cv.u;
}

DEVI void gload16(const void* gptr, void* lptr) {
  __builtin_amdgcn_global_load_lds(
      (const __attribute__((address_space(1))) unsigned int*)gptr,
      (__attribute__((address_space(3))) unsigned int*)(unsigned long long)(uintptr_t)lptr,
      16, 0, 0);
}

// ---------------- weight conversion ----------------
__global__ void cvt_bf16_kernel(const float* __restrict__ src,
                                unsigned short* __restrict__ dst, size_t n) {
  size_t i = (size_t)blockIdx.x * blockDim.x + threadIdx.x;
  if (i < n) dst[i] = f2bf(src[i]);
}

// pred_w (94x1024) -> padded (96x1024) bf16, rows 94..95 zero
__global__ void cvt_pad_pred_kernel(const float* __restrict__ src,
                                    unsigned short* __restrict__ dst) {
  int i = blockIdx.x * blockDim.x + threadIdx.x;
  if (i >= 96 * 1024) return;
  int row = i >> 10;
  dst[i] = (row < 94) ? f2bf(src[i]) : (unsigned short)0;
}

// ---------------- ROI align v4: separable weights -> per-box MFMA GEMM ----------------
// Out[ch][cell] = sum_{rc} P[ch][rc] * W[cell][rc], rc = r*16+c of the 16x16 patch,
// W[cell][rc] = WY[py][r]*WX[px][c], WY[py][r] = 0.5*(wy(2py,r)+wy(2py+1,r)).
// grid (2048 boxes, 4 channel-quarters of 64). 256 threads = 4 waves (2x2 of 32x32).
__global__ __launch_bounds__(256) void roi_align_mfma(
    const float* __restrict__ p3, const float* __restrict__ p4,
    const float* __restrict__ p5, const float* __restrict__ bbox,
    const int* __restrict__ aid, unsigned short* __restrict__ X) {
  constexpr int SP = 264;              // bf16 row stride (256 + 8 pad)
  const int box = blockIdx.x;          // 0..2047
  const int cq = blockIdx.y;           // channel quarter 0..3
  const int b = box >> 9;
  const int tid = threadIdx.x;
  __shared__ int sy0[14], sx0[14];
  __shared__ float sly[14], slx[14];
  __shared__ float wy[7][16], wx[7][16];
  __shared__ unsigned short P[64 * SP];   // 33.8 KB
  __shared__ unsigned short W[64 * SP];   // 33.8 KB (rows 49..63 garbage, never stored)

  const int lvl = aid[box] / 3;
  const float* base;
  int H;
  if (lvl == 0)      { base = p3; H = 64; }
  else if (lvl == 1) { base = p4; H = 32; }
  else               { base = p5; H = 16; }
  const float scale = 0.125f / (float)(1 << lvl);

  // ---- phase A: sample grid ----
  if (tid < 28) {
    int s = tid;
    bool isY = s < 14;
    int k = isY ? s : s - 14;
    float lo = bbox[box * 4 + (isY ? 0 : 1)];
    float hi = bbox[box * 4 + (isY ? 2 : 3)];
    float t = lo * scale - 0.5f;
    float cell = (hi - lo) * scale * (1.0f / 7.0f);
    float pos = t + ((float)k + 0.5f) * 0.5f * cell;
    pos = fminf(fmaxf(pos, 0.0f), (float)(H - 1));
    int i0 = (int)floorf(pos);
    if (i0 > H - 2) i0 = H - 2;        // fr=1 reproduces the clamp
    float fr = pos - (float)i0;
    if (isY) { sy0[k] = i0; sly[k] = fr; }
    else     { sx0[k] = i0; slx[k] = fr; }
  }
  __syncthreads();

  const int ry0 = sy0[0], rx0 = sx0[0];   // monotone grid -> minima
  const int HH = H * H;
  const float* fb = base + (size_t)b * 256 * HH + (size_t)cq * 64 * HH;

  // ---- phase B: separable pooled weights (7x16 each) + P staging ----
  if (tid < 224) {
    int j = tid;
    bool isY = j < 112;
    int k = isY ? j : j - 112;
    int py = k >> 4, r = k & 15;
    int o0 = isY ? ry0 : rx0;
    float acc = 0.f;
#pragma unroll
    for (int ss = 0; ss < 2; ++ss) {
      int s = 2 * py + ss;
      int rel = (isY ? sy0[s] : sx0[s]) - o0;
      float fr = isY ? sly[s] : slx[s];
      if (r == rel)     acc += 1.0f - fr;
      if (r == rel + 1) acc += fr;
    }
    if (isY) wy[py][r] = acc * 0.5f;
    else     wx[py][r] = acc * 0.5f;
  }

  {
    const int ch = tid >> 2;             // 0..63
    const int rblk = (tid & 3) * 4;
    const float* fp = fb + (size_t)ch * HH;
#pragma unroll
    for (int rr = 0; rr < 4; ++rr) {
      int r = rblk + rr;
      int gy = min(ry0 + r, H - 1);
      const float* rowp = fp + gy * H;
      float v[16];
#pragma unroll
      for (int c = 0; c < 16; ++c)
        v[c] = rowp[min(rx0 + c, H - 1)];
      unsigned int d[8];
#pragma unroll
      for (int k = 0; k < 8; ++k)
        d[k] = (unsigned int)f2bf(v[2 * k]) | ((unsigned int)f2bf(v[2 * k + 1]) << 16);
      unsigned int* dst = (unsigned int*)&P[ch * SP + r * 16];
      *(uint4*)dst = make_uint4(d[0], d[1], d[2], d[3]);
      *(uint4*)(dst + 4) = make_uint4(d[4], d[5], d[6], d[7]);
    }
  }
  __syncthreads();

  // ---- phase C: W fill (49 valid cells x 128 dwords) ----
  for (int idx = tid; idx < 49 * 128; idx += 256) {
    int cell = idx >> 7;
    int d = idx & 127;
    int r = d >> 3;
    int c = (d & 7) * 2;
    int py = (cell * 37) >> 8;           // cell/7 for 0..55
    int px = cell - py * 7;
    float a = wy[py][r];
    unsigned int pk = (unsigned int)f2bf(a * wx[px][c]) |
                      ((unsigned int)f2bf(a * wx[px][c + 1]) << 16);
    *(unsigned int*)&W[cell * SP + d * 2] = pk;
  }
  __syncthreads();

  // ---- phase D: GEMM Out(64x64) = P(64x256) @ W(64x256)^T ----
  const int lane = tid & 63, wid = tid >> 6;
  const int wm = wid >> 1, wn = wid & 1;   // 2x2 waves, 32x32 each
  const int fr = lane & 15, fg = lane >> 4;

  floatx4 acc[2][2];
#pragma unroll
  for (int i = 0; i < 2; ++i)
#pragma unroll
    for (int j = 0; j < 2; ++j)
      acc[i][j] = (floatx4){0.f, 0.f, 0.f, 0.f};

#pragma unroll
  for (int kk = 0; kk < 8; ++kk) {
    short8 af[2], bw[2];
#pragma unroll
    for (int i = 0; i < 2; ++i)
      af[i] = *reinterpret_cast<const short8*>(&P[(wm * 32 + i * 16 + fr) * SP + kk * 32 + fg * 8]);
#pragma unroll
    for (int j = 0; j < 2; ++j)
      bw[j] = *reinterpret_cast<const short8*>(&W[(wn * 32 + j * 16 + fr) * SP + kk * 32 + fg * 8]);
#pragma unroll
    for (int i = 0; i < 2; ++i)
#pragma unroll
      for (int j = 0; j < 2; ++j)
        acc[i][j] = __builtin_amdgcn_mfma_f32_16x16x32_bf16(af[i], bw[j], acc[i][j], 0, 0, 0);
  }

  unsigned short* xb = X + (size_t)box * 12544 + (size_t)(cq * 64) * 49;
#pragma unroll
  for (int i = 0; i < 2; ++i)
#pragma unroll
    for (int j = 0; j < 2; ++j)
#pragma unroll
      for (int q = 0; q < 4; ++q) {
        int m = wm * 32 + i * 16 + fg * 4 + q;   // channel
        int cell = wn * 32 + j * 16 + fr;        // 0..63
        if (cell < 49)
          xb[m * 49 + cell] = f2bf(acc[i][j][q]);
      }
}

// ---------------- GEMM v2: 128x128 tile, BK=64, T2 XOR-swizzle, split-K ----------------
template <int KSPLIT>
__global__ __launch_bounds__(256) void gemm_bt_swz(
    const unsigned short* __restrict__ A, const unsigned short* __restrict__ Bw,
    float* __restrict__ C, int M, int N, int K) {
  constexpr int BM = 128, BN = 128, BK = 64;
  __shared__ unsigned short As[BM * BK];   // 16 KB
  __shared__ unsigned short Bs[BN * BK];   // 16 KB

  const int tid = threadIdx.x;
  const int lane = tid & 63, wid = tid >> 6;
  const int wr = wid >> 1, wc = wid & 1;    // 2x2 waves, 64x64 each
  const int tm = blockIdx.x * BM, tn = blockIdx.y * BN;
  const int fr = lane & 15, fg = lane >> 4;

  const int kLen = K / KSPLIT;
  const int kTiles = kLen / BK;
  const int kBeg = blockIdx.z * kLen;
  float* Cz = C + (size_t)blockIdx.z * M * N;

  floatx4 acc[4][4];
#pragma unroll
  for (int i = 0; i < 4; ++i)
#pragma unroll
    for (int j = 0; j < 4; ++j)
      acc[i][j] = (floatx4){0.f, 0.f, 0.f, 0.f};

  for (int t = 0; t < kTiles; ++t) {
    const int k0 = kBeg + t * BK;
#pragma unroll
    for (int s = tid; s < BM * 8; s += 256) {
      int row = s >> 3, sl = s & 7;
      int slg = sl ^ (row & 7);
      gload16(&A[(size_t)(tm + row) * K + k0 + slg * 8], &As[s * 8]);
    }
#pragma unroll
    for (int s = tid; s < BN * 8; s += 256) {
      int row = s >> 3, sl = s & 7;
      int slg = sl ^ (row & 7);
      gload16(&Bw[(size_t)(tn + row) * K + k0 + slg * 8], &Bs[s * 8]);
    }
    __syncthreads();

#pragma unroll
    for (int kk = 0; kk < 2; ++kk) {
      short8 af[4], bf[4];
#pragma unroll
      for (int i = 0; i < 4; ++i) {
        int row = wr * 64 + i * 16 + fr;
        int sl = (kk * 4 + fg) ^ (row & 7);
        af[i] = *reinterpret_cast<const short8*>(&As[(row * 8 + sl) * 8]);
      }
#pragma unroll
      for (int j = 0; j < 4; ++j) {
        int row = wc * 64 + j * 16 + fr;
        int sl = (kk * 4 + fg) ^ (row & 7);
        bf[j] = *reinterpret_cast<const short8*>(&Bs[(row * 8 + sl) * 8]);
      }
#pragma unroll
      for (int i = 0; i < 4; ++i)
#pragma unroll
        for (int j = 0; j < 4; ++j)
          acc[i][j] = __builtin_amdgcn_mfma_f32_16x16x32_bf16(af[i], bf[j], acc[i][j], 0, 0, 0);
    }
    __syncthreads();
  }

#pragma unroll
  for (int i = 0; i < 4; ++i)
#pragma unroll
    for (int j = 0; j < 4; ++j)
#pragma unroll
      for (int q = 0; q < 4; ++q) {
        int rr = tm + wr * 64 + i * 16 + fg * 4 + q;
        int cc = tn + wc * 64 + j * 16 + fr;
        Cz[(size_t)rr * N + cc] = acc[i][j][q];
      }
}

// ---------------- old GEMM (pred head only) ----------------
template <int BM, int BN, int WAVES_M, int WAVES_N, int KSPLIT>
__global__ __launch_bounds__(256) void gemm_bt_kernel(
    const unsigned short* __restrict__ A, const unsigned short* __restrict__ Bw,
    float* __restrict__ C, int M, int N, int K) {
  constexpr int BK = 32;
  constexpr int WM = BM / WAVES_M, WN = BN / WAVES_N;
  constexpr int AF = WM / 16, BF = WN / 16;
  constexpr int ASLOT = BM * 4;
  constexpr int BSLOT = BN * 4;
  __shared__ unsigned short As[BM * BK];
  __shared__ unsigned short Bs[BN * BK];

  const int tid = threadIdx.x;
  const int lane = tid & 63, wid = tid >> 6;
  const int wr = wid / WAVES_N, wc = wid % WAVES_N;
  const int tm = blockIdx.x * BM, tn = blockIdx.y * BN;
  const int fr = lane & 15, fg = lane >> 4;

  const int kLen = K / KSPLIT;
  const int kBeg = blockIdx.z * kLen;
  float* Cz = C + (size_t)blockIdx.z * M * N;

  floatx4 acc[AF][BF];
#pragma unroll
  for (int i = 0; i < AF; ++i)
#pragma unroll
    for (int j = 0; j < BF; ++j)
      acc[i][j] = (floatx4){0.f, 0.f, 0.f, 0.f};

  for (int k0 = kBeg; k0 < kBeg + kLen; k0 += BK) {
#pragma unroll
    for (int s = tid; s < ASLOT; s += 256) {
      int row = s >> 2, kb = (s & 3) << 3;
      gload16(&A[(size_t)(tm + row) * K + k0 + kb], &As[s * 8]);
    }
#pragma unroll
    for (int s = tid; s < BSLOT; s += 256) {
      int row = s >> 2, kb = (s & 3) << 3;
      gload16(&Bw[(size_t)(tn + row) * K + k0 + kb], &Bs[s * 8]);
    }
    __syncthreads();

    short8 af[AF], bfv[BF];
#pragma unroll
    for (int i = 0; i < AF; ++i)
      af[i] = *reinterpret_cast<const short8*>(&As[(wr * WM + i * 16 + fr) * BK + fg * 8]);
#pragma unroll
    for (int j = 0; j < BF; ++j)
      bfv[j] = *reinterpret_cast<const short8*>(&Bs[(wc * WN + j * 16 + fr) * BK + fg * 8]);
#pragma unroll
    for (int i = 0; i < AF; ++i)
#pragma unroll
      for (int j = 0; j < BF; ++j)
        acc[i][j] = __builtin_amdgcn_mfma_f32_16x16x32_bf16(af[i], bfv[j], acc[i][j], 0, 0, 0);
    __syncthreads();
  }

#pragma unroll
  for (int i = 0; i < AF; ++i)
#pragma unroll
    for (int j = 0; j < BF; ++j)
#pragma unroll
      for (int q = 0; q < 4; ++q) {
        int rr = tm + wr * WM + i * 16 + fg * 4 + q;
        int cc = tn + wc * WN + j * 16 + fr;
        Cz[(size_t)rr * N + cc] = acc[i][j][q];
      }
}

// ---------------- BatchNorm (train mode) ----------------
__global__ void bn_stats_red_kernel(const float* __restrict__ Yp, float* __restrict__ Yred,
                                    float* __restrict__ psum, float* __restrict__ psq,
                                    int Ncols, int rowsPer, int P, size_t pstride) {
  int c = blockIdx.x * blockDim.x + threadIdx.x;
  int r0 = blockIdx.y * rowsPer;
  float s = 0.f, ss = 0.f;
  for (int r = 0; r < rowsPer; ++r) {
    size_t idx = (size_t)(r0 + r) * Ncols + c;
    float v = Yp[idx];
    for (int p = 1; p < P; ++p) v += Yp[idx + (size_t)p * pstride];
    Yred[idx] = v;
    s += v;
    ss += v * v;
  }
  psum[(size_t)blockIdx.y * Ncols + c] = s;
  psq[(size_t)blockIdx.y * Ncols + c] = ss;
}

__global__ void bn_finalize_kernel(const float* __restrict__ psum, const float* __restrict__ psq,
                                   const float* __restrict__ g, const float* __restrict__ b,
                                   float* __restrict__ scale, float* __restrict__ shift,
                                   int Ncols, int P, float invM) {
  int c = blockIdx.x * blockDim.x + threadIdx.x;
  if (c >= Ncols) return;
  float s = 0.f, ss = 0.f;
  for (int p = 0; p < P; ++p) {
    s += psum[(size_t)p * Ncols + c];
    ss += psq[(size_t)p * Ncols + c];
  }
  float mean = s * invM;
  float var = ss * invM - mean * mean;
  float rstd = rsqrtf(var + 1e-5f);
  float sc = rstd * g[c];
  scale[c] = sc;
  shift[c] = b[c] - mean * sc;
}

__global__ void bn_apply_kernel(const float* __restrict__ Y, const float* __restrict__ scale,
                                const float* __restrict__ shift, unsigned short* __restrict__ X,
                                int NcolsMask, int total) {
  int i = blockIdx.x * blockDim.x + threadIdx.x;
  if (i >= total) return;
  int c = i & NcolsMask;
  float v = Y[i] * scale[c] + shift[c];
  v = fmaxf(v, 0.0f);
  X[i] = f2bf(v);
}

// ---------------- decode ----------------
// Y3 holds KSPLIT=4 partials of (2048 x 96)
__global__ void decode_kernel(const float* __restrict__ Y3, const float* __restrict__ pb,
                              const float* __restrict__ anchors, const int* __restrict__ aid,
                              float* __restrict__ out) {
  int i = blockIdx.x * blockDim.x + threadIdx.x;
  if (i >= 2048 * 94) return;
  int bn = i / 94;
  int ch = i - bn * 94;
  size_t idx = (size_t)bn * 96 + ch;
  float v = Y3[idx] + Y3[idx + 2048 * 96] + Y3[idx + 2 * 2048 * 96] + Y3[idx + 3 * 2048 * 96];
  v += pb[ch];
  float o = v;
  if (ch >= 4 && ch < 22) {
    int q = ch - 4;
    int d = q % 6;   // within-class: 0,1=yx 2,3=lw 4,5=zh
    if (d < 2) {
      float stride_px = (float)(8 << (aid[bn] / 3));
      o = anchors[(size_t)bn * 4 + d] + v * stride_px;
    } else if (d < 4) {
      float cl = fminf(fmaxf(v, -4.0f), 4.0f);
      o = anchors[(size_t)bn * 4 + d] * expf(cl);
    }
  }
  out[i] = o;
}

// ---------------- launch ----------------
extern "C" void kernel_launch(void* const* d_in, const int* in_sizes, int n_in,
                              void* d_out, int out_size, void* d_ws, size_t ws_size,
                              hipStream_t stream) {
  const float* feat_p3   = (const float*)d_in[0];
  const float* feat_p4   = (const float*)d_in[1];
  const float* feat_p5   = (const float*)d_in[2];
  const float* bbox2d    = (const float*)d_in[3];
  const float* anchors   = (const float*)d_in[4];
  const int*   anchor_id = (const int*)d_in[5];
  const float* fc1_w     = (const float*)d_in[6];
  // d_in[7] fc1_b: cancels through train-mode BN (mean subtraction) — unused
  const float* bn1_g     = (const float*)d_in[8];
  const float* bn1_b     = (const float*)d_in[9];
  const float* fc2_w     = (const float*)d_in[10];
  // d_in[11] fc2_b: cancels — unused
  const float* bn2_g     = (const float*)d_in[12];
  const float* bn2_b     = (const float*)d_in[13];
  const float* pred_w    = (const float*)d_in[14];
  const float* pred_b    = (const float*)d_in[15];
  float* out = (float*)d_out;

  const int M = 2048;          // B*N
  const int K1 = 12544;        // 256*7*7
  const int FC = 1024;

  char* ws = (char*)d_ws;
  auto alloc = [&](size_t bytes) -> char* {
    char* p = ws;
    ws += (bytes + 255) & ~(size_t)255;
    return p;
  };
  unsigned short* W1b = (unsigned short*)alloc((size_t)FC * K1 * 2);
  unsigned short* W2b = (unsigned short*)alloc((size_t)FC * FC * 2);
  unsigned short* W3b = (unsigned short*)alloc((size_t)96 * FC * 2);
  unsigned short* X1  = (unsigned short*)alloc((size_t)M * K1 * 2);
  float*          Yp  = (float*)alloc((size_t)4 * M * FC * 4);  // split-K partials
  float*          Yr  = (float*)alloc((size_t)M * FC * 4);      // reduced Y
  unsigned short* X2  = (unsigned short*)alloc((size_t)M * FC * 2);
  unsigned short* X3  = (unsigned short*)alloc((size_t)M * FC * 2);
  float*          Y3  = (float*)alloc((size_t)4 * M * 96 * 4);
  float*          ps  = (float*)alloc((size_t)16 * FC * 4);
  float*          pq  = (float*)alloc((size_t)16 * FC * 4);
  float*          sc1 = (float*)alloc((size_t)FC * 4);
  float*          sh1 = (float*)alloc((size_t)FC * 4);
  float*          sc2 = (float*)alloc((size_t)FC * 4);
  float*          sh2 = (float*)alloc((size_t)FC * 4);

  // weight conversions (must redo each call — no cross-call state allowed)
  {
    size_t n = (size_t)FC * K1;
    cvt_bf16_kernel<<<(unsigned)((n + 255) / 256), 256, 0, stream>>>(fc1_w, W1b, n);
  }
  {
    size_t n = (size_t)FC * FC;
    cvt_bf16_kernel<<<(unsigned)((n + 255) / 256), 256, 0, stream>>>(fc2_w, W2b, n);
  }
  cvt_pad_pred_kernel<<<(96 * 1024) / 256, 256, 0, stream>>>(pred_w, W3b);

  // ROI align -> X1 (2048 x 12544) bf16
  roi_align_mfma<<<dim3(2048, 4), 256, 0, stream>>>(feat_p3, feat_p4, feat_p5, bbox2d, anchor_id, X1);

  // fc1: X1 (2048x12544) @ W1^T -> Yp (4 partials of 2048x1024)
  gemm_bt_swz<4><<<dim3(M / 128, FC / 128, 4), 256, 0, stream>>>(X1, W1b, Yp, M, FC, K1);

  // BN1: reduce partials + stats, finalize, apply+ReLU -> X2 bf16
  bn_stats_red_kernel<<<dim3(FC / 256, 16), 256, 0, stream>>>(Yp, Yr, ps, pq, FC, M / 16, 4, (size_t)M * FC);
  bn_finalize_kernel<<<FC / 256, 256, 0, stream>>>(ps, pq, bn1_g, bn1_b, sc1, sh1, FC, 16, 1.0f / M);
  bn_apply_kernel<<<(M * FC) / 256, 256, 0, stream>>>(Yr, sc1, sh1, X2, FC - 1, M * FC);

  // fc2: X2 @ W2^T -> Yp (2 partials)
  gemm_bt_swz<2><<<dim3(M / 128, FC / 128, 2), 256, 0, stream>>>(X2, W2b, Yp, M, FC, FC);

  // BN2 + ReLU -> X3 bf16
  bn_stats_red_kernel<<<dim3(FC / 256, 16), 256, 0, stream>>>(Yp, Yr, ps, pq, FC, M / 16, 2, (size_t)M * FC);
  bn_finalize_kernel<<<FC / 256, 256, 0, stream>>>(ps, pq, bn2_g, bn2_b, sc2, sh2, FC, 16, 1.0f / M);
  bn_apply_kernel<<<(M * FC) / 256, 256, 0, stream>>>(Yr, sc2, sh2, X3, FC - 1, M * FC);

  // pred head: X3 @ W3p^T -> Y3 (split-K=4 partials of 2048 x 96)
  gemm_bt_kernel<64, 96, 2, 2, 4><<<dim3(M / 64, 1, 4), 256, 0, stream>>>(X3, W3b, Y3, M, 96, FC);

  // decode -> out (2048 x 94)
  decode_kernel<<<(2048 * 94 + 255) / 256, 256, 0, stream>>>(Y3, pred_b, anchors, anchor_id, out);
}

// Round 6
// 381.207 us; speedup vs baseline: 1.3601x; 1.3601x over previous
//
#include <hip/hip_runtime.h>
#include <hip/hip_bf16.h>

typedef __attribute__((ext_vector_type(8))) short short8;
typedef __attribute__((ext_vector_type(4))) float floatx4;

#define DEVI __device__ __forceinline__

// ---------------- constants ----------------
// B=4, N=512, C_IN=256, RES=7, SR=2, FC_DIM=1024, OUT_CH=94
// M = B*N = 2048 rows, K1 = 256*7*7 = 12544

DEVI unsigned short f2bf(float v) {
  union { __hip_bfloat16 h; unsigned short u; } cv;
  cv.h = __float2bfloat16(v);
  return cv.u;
}
DEVI short f2bfs(float v) { return (short)f2bf(v); }

DEVI void gload16(const void* gptr, void* lptr) {
  __builtin_amdgcn_global_load_lds(
      (const __attribute__((address_space(1))) unsigned int*)gptr,
      (__attribute__((address_space(3))) unsigned int*)(unsigned long long)(uintptr_t)lptr,
      16, 0, 0);
}

// ---------------- weight conversion ----------------
__global__ void cvt_bf16_kernel(const float* __restrict__ src,
                                unsigned short* __restrict__ dst, size_t n) {
  size_t i = (size_t)blockIdx.x * blockDim.x + threadIdx.x;
  if (i < n) dst[i] = f2bf(src[i]);
}

// pred_w (94x1024) -> padded (96x1024) bf16, rows 94..95 zero
__global__ void cvt_pad_pred_kernel(const float* __restrict__ src,
                                    unsigned short* __restrict__ dst) {
  int i = blockIdx.x * blockDim.x + threadIdx.x;
  if (i >= 96 * 1024) return;
  int row = i >> 10;
  dst[i] = (row < 94) ? f2bf(src[i]) : (unsigned short)0;
}

// ---------------- ROI align: W generation (per box) ----------------
// Separable pooled weights: Out[ch][py,px] = sum_{r,c} P[ch][r,c]*WY[py][r]*WX[px][c].
// W[cell][k=r*16+c] = WY[py][r]*WX[px][c], stored bf16 with row stride 264 (bank pad).
// Patch origin (ry,rx) = min(grid_min, H-16) so the 16x16 patch is fully in-bounds.
__global__ __launch_bounds__(256) void wgen_kernel(
    const float* __restrict__ bbox, const int* __restrict__ aid,
    unsigned short* __restrict__ Wbuf, int2* __restrict__ rbase) {
  const int box = blockIdx.x;
  const int tid = threadIdx.x;
  __shared__ int sy0[14], sx0[14];
  __shared__ float sly[14], slx[14];
  __shared__ float wy[7][16], wx[7][16];

  const int lvl = aid[box] / 3;
  const int H = 64 >> lvl;
  const float scale = 0.125f / (float)(1 << lvl);

  if (tid < 28) {
    int s = tid;
    bool isY = s < 14;
    int k = isY ? s : s - 14;
    float lo = bbox[box * 4 + (isY ? 0 : 1)];
    float hi = bbox[box * 4 + (isY ? 2 : 3)];
    float t = lo * scale - 0.5f;
    float cell = (hi - lo) * scale * (1.0f / 7.0f);
    float pos = t + ((float)k + 0.5f) * 0.5f * cell;   // S=14 samples, SR=2
    pos = fminf(fmaxf(pos, 0.0f), (float)(H - 1));
    int i0 = (int)floorf(pos);
    if (i0 > H - 2) i0 = H - 2;        // fr=1 reproduces the clamp
    float fr = pos - (float)i0;
    if (isY) { sy0[k] = i0; sly[k] = fr; }
    else     { sx0[k] = i0; slx[k] = fr; }
  }
  __syncthreads();

  const int ryb = min(sy0[0], H - 16);   // grid is monotone -> sy0[0]/sx0[0] are minima
  const int rxb = min(sx0[0], H - 16);
  if (tid == 0) rbase[box] = make_int2(ryb, rxb);

  if (tid < 224) {
    int j = tid;
    bool isY = j < 112;
    int k2 = isY ? j : j - 112;
    int py = k2 >> 4, r = k2 & 15;
    int o0 = isY ? ryb : rxb;
    float acc = 0.f;
#pragma unroll
    for (int ss = 0; ss < 2; ++ss) {
      int s = 2 * py + ss;
      int rel = (isY ? sy0[s] : sx0[s]) - o0;
      float fr = isY ? sly[s] : slx[s];
      if (r == rel)     acc += 1.0f - fr;
      if (r == rel + 1) acc += fr;
    }
    if (isY) wy[py][r] = acc * 0.5f;
    else     wx[py][r] = acc * 0.5f;
  }
  __syncthreads();

  unsigned short* wb = Wbuf + (size_t)box * 13312;   // 26624 B per box
  for (int idx = tid; idx < 49 * 256; idx += 256) {
    int cell = idx >> 8, k = idx & 255;
    int r = k >> 4, c = k & 15;
    int py = (cell * 37) >> 8;   // cell/7 for 0..55
    int px = cell - py * 7;
    wb[cell * 264 + k] = f2bf(wy[py][r] * wx[px][c]);
  }
}

// ---------------- ROI align: per-box MFMA GEMM ----------------
// grid (2048 boxes, 8 channel-octets of 32). 256 threads = 4 waves.
// P: 32ch x 16x16 patch, f32 in LDS (stride 260 -> conflict-free A-frag reads),
// staged via global_load_lds (1 wave-op = 1 channel's 1KB patch, linear LDS dest).
// W: staged via global_load_lds from Wbuf (identical byte layout, stride 264 bf16).
// Out(32ch x 49cells) = cvt_bf16(P) @ W^T via 16x16x32 MFMA, K=256.
__global__ __launch_bounds__(256) void roi_mm_kernel(
    const float* __restrict__ p3, const float* __restrict__ p4,
    const float* __restrict__ p5, const unsigned short* __restrict__ Wbuf,
    const int2* __restrict__ rbase, const int* __restrict__ aid,
    unsigned short* __restrict__ X) {
  constexpr int PS = 260;   // f32 per-channel stride
  constexpr int WS = 264;   // bf16 per-cell stride
  __shared__ float P[32 * PS];             // 33280 B
  __shared__ unsigned short W[64 * WS];    // 33792 B (rows >=51 uninit, masked)

  const int box = blockIdx.x;
  const int oct = blockIdx.y;              // channels oct*32 ..
  const int b = box >> 9;
  const int tid = threadIdx.x;
  const int lane = tid & 63, wid = tid >> 6;

  const int lvl = aid[box] / 3;
  const int H = 64 >> lvl;
  const int HH = H * H;
  const float* base = (lvl == 0) ? p3 : ((lvl == 1) ? p4 : p5);
  const int2 rb = rbase[box];
  const float* fb = base + ((size_t)b * 256 + oct * 32) * HH + rb.x * H + rb.y;

  // stage W: 1664 slots x 16B = 26624 B (wave-uniform activity: 1664 = 6.5*256)
  const unsigned short* wsrc = Wbuf + (size_t)box * 13312;
  for (int s = tid; s < 1664; s += 256)
    gload16(wsrc + s * 8, (unsigned short*)W + s * 8);

  // stage P: per wave-iteration one channel; lane l -> (row l>>2, col4 l&3)
  {
    const int r = lane >> 2, c4 = (lane & 3) * 4;
    const float* src0 = fb + r * H + c4;
#pragma unroll
    for (int it = 0; it < 8; ++it) {
      int ch = it * 4 + wid;
      gload16(src0 + (size_t)ch * HH, &P[ch * PS] + lane * 4);
    }
  }
  __syncthreads();

  // MFMA: wave -> ch-frag (wid>>1), cell-half (wid&1)
  const int fr = lane & 15, fg = lane >> 4;
  const int chf = wid >> 1;
  const int cellb = (wid & 1) * 32;

  floatx4 acc0 = (floatx4){0.f, 0.f, 0.f, 0.f};
  floatx4 acc1 = (floatx4){0.f, 0.f, 0.f, 0.f};

#pragma unroll
  for (int kk = 0; kk < 8; ++kk) {
    const float* ap = &P[(chf * 16 + fr) * PS + kk * 32 + fg * 8];
    floatx4 a0 = *(const floatx4*)ap;
    floatx4 a1 = *(const floatx4*)(ap + 4);
    short8 af;
    af[0] = f2bfs(a0[0]); af[1] = f2bfs(a0[1]); af[2] = f2bfs(a0[2]); af[3] = f2bfs(a0[3]);
    af[4] = f2bfs(a1[0]); af[5] = f2bfs(a1[1]); af[6] = f2bfs(a1[2]); af[7] = f2bfs(a1[3]);
    short8 b0 = *(const short8*)&W[(cellb + fr) * WS + kk * 32 + fg * 8];
    short8 b1 = *(const short8*)&W[(cellb + 16 + fr) * WS + kk * 32 + fg * 8];
    acc0 = __builtin_amdgcn_mfma_f32_16x16x32_bf16(af, b0, acc0, 0, 0, 0);
    acc1 = __builtin_amdgcn_mfma_f32_16x16x32_bf16(af, b1, acc1, 0, 0, 0);
  }

  unsigned short* xb = X + (size_t)box * 12544 + (size_t)(oct * 32 + chf * 16) * 49;
  {
    int cell = cellb + fr;
    if (cell < 49) {
#pragma unroll
      for (int q = 0; q < 4; ++q)
        xb[(fg * 4 + q) * 49 + cell] = f2bf(acc0[q]);
    }
    cell = cellb + 16 + fr;
    if (cell < 49) {
#pragma unroll
      for (int q = 0; q < 4; ++q)
        xb[(fg * 4 + q) * 49 + cell] = f2bf(acc1[q]);
    }
  }
}

// ---------------- GEMM v2: 128x128 tile, BK=64, T2 XOR-swizzle, split-K ----------------
template <int KSPLIT>
__global__ __launch_bounds__(256) void gemm_bt_swz(
    const unsigned short* __restrict__ A, const unsigned short* __restrict__ Bw,
    float* __restrict__ C, int M, int N, int K) {
  constexpr int BM = 128, BN = 128, BK = 64;
  __shared__ unsigned short As[BM * BK];   // 16 KB
  __shared__ unsigned short Bs[BN * BK];   // 16 KB

  const int tid = threadIdx.x;
  const int lane = tid & 63, wid = tid >> 6;
  const int wr = wid >> 1, wc = wid & 1;    // 2x2 waves, 64x64 each
  const int tm = blockIdx.x * BM, tn = blockIdx.y * BN;
  const int fr = lane & 15, fg = lane >> 4;

  const int kLen = K / KSPLIT;
  const int kTiles = kLen / BK;
  const int kBeg = blockIdx.z * kLen;
  float* Cz = C + (size_t)blockIdx.z * M * N;

  floatx4 acc[4][4];
#pragma unroll
  for (int i = 0; i < 4; ++i)
#pragma unroll
    for (int j = 0; j < 4; ++j)
      acc[i][j] = (floatx4){0.f, 0.f, 0.f, 0.f};

  for (int t = 0; t < kTiles; ++t) {
    const int k0 = kBeg + t * BK;
#pragma unroll
    for (int s = tid; s < BM * 8; s += 256) {
      int row = s >> 3, sl = s & 7;
      int slg = sl ^ (row & 7);
      gload16(&A[(size_t)(tm + row) * K + k0 + slg * 8], &As[s * 8]);
    }
#pragma unroll
    for (int s = tid; s < BN * 8; s += 256) {
      int row = s >> 3, sl = s & 7;
      int slg = sl ^ (row & 7);
      gload16(&Bw[(size_t)(tn + row) * K + k0 + slg * 8], &Bs[s * 8]);
    }
    __syncthreads();

#pragma unroll
    for (int kk = 0; kk < 2; ++kk) {
      short8 af[4], bf[4];
#pragma unroll
      for (int i = 0; i < 4; ++i) {
        int row = wr * 64 + i * 16 + fr;
        int sl = (kk * 4 + fg) ^ (row & 7);
        af[i] = *reinterpret_cast<const short8*>(&As[(row * 8 + sl) * 8]);
      }
#pragma unroll
      for (int j = 0; j < 4; ++j) {
        int row = wc * 64 + j * 16 + fr;
        int sl = (kk * 4 + fg) ^ (row & 7);
        bf[j] = *reinterpret_cast<const short8*>(&Bs[(row * 8 + sl) * 8]);
      }
#pragma unroll
      for (int i = 0; i < 4; ++i)
#pragma unroll
        for (int j = 0; j < 4; ++j)
          acc[i][j] = __builtin_amdgcn_mfma_f32_16x16x32_bf16(af[i], bf[j], acc[i][j], 0, 0, 0);
    }
    __syncthreads();
  }

#pragma unroll
  for (int i = 0; i < 4; ++i)
#pragma unroll
    for (int j = 0; j < 4; ++j)
#pragma unroll
      for (int q = 0; q < 4; ++q) {
        int rr = tm + wr * 64 + i * 16 + fg * 4 + q;
        int cc = tn + wc * 64 + j * 16 + fr;
        Cz[(size_t)rr * N + cc] = acc[i][j][q];
      }
}

// ---------------- old GEMM (pred head only) ----------------
template <int BM, int BN, int WAVES_M, int WAVES_N, int KSPLIT>
__global__ __launch_bounds__(256) void gemm_bt_kernel(
    const unsigned short* __restrict__ A, const unsigned short* __restrict__ Bw,
    float* __restrict__ C, int M, int N, int K) {
  constexpr int BK = 32;
  constexpr int WM = BM / WAVES_M, WN = BN / WAVES_N;
  constexpr int AF = WM / 16, BF = WN / 16;
  constexpr int ASLOT = BM * 4;
  constexpr int BSLOT = BN * 4;
  __shared__ unsigned short As[BM * BK];
  __shared__ unsigned short Bs[BN * BK];

  const int tid = threadIdx.x;
  const int lane = tid & 63, wid = tid >> 6;
  const int wr = wid / WAVES_N, wc = wid % WAVES_N;
  const int tm = blockIdx.x * BM, tn = blockIdx.y * BN;
  const int fr = lane & 15, fg = lane >> 4;

  const int kLen = K / KSPLIT;
  const int kBeg = blockIdx.z * kLen;
  float* Cz = C + (size_t)blockIdx.z * M * N;

  floatx4 acc[AF][BF];
#pragma unroll
  for (int i = 0; i < AF; ++i)
#pragma unroll
    for (int j = 0; j < BF; ++j)
      acc[i][j] = (floatx4){0.f, 0.f, 0.f, 0.f};

  for (int k0 = kBeg; k0 < kBeg + kLen; k0 += BK) {
#pragma unroll
    for (int s = tid; s < ASLOT; s += 256) {
      int row = s >> 2, kb = (s & 3) << 3;
      gload16(&A[(size_t)(tm + row) * K + k0 + kb], &As[s * 8]);
    }
#pragma unroll
    for (int s = tid; s < BSLOT; s += 256) {
      int row = s >> 2, kb = (s & 3) << 3;
      gload16(&Bw[(size_t)(tn + row) * K + k0 + kb], &Bs[s * 8]);
    }
    __syncthreads();

    short8 af[AF], bfv[BF];
#pragma unroll
    for (int i = 0; i < AF; ++i)
      af[i] = *reinterpret_cast<const short8*>(&As[(wr * WM + i * 16 + fr) * BK + fg * 8]);
#pragma unroll
    for (int j = 0; j < BF; ++j)
      bfv[j] = *reinterpret_cast<const short8*>(&Bs[(wc * WN + j * 16 + fr) * BK + fg * 8]);
#pragma unroll
    for (int i = 0; i < AF; ++i)
#pragma unroll
      for (int j = 0; j < BF; ++j)
        acc[i][j] = __builtin_amdgcn_mfma_f32_16x16x32_bf16(af[i], bfv[j], acc[i][j], 0, 0, 0);
    __syncthreads();
  }

#pragma unroll
  for (int i = 0; i < AF; ++i)
#pragma unroll
    for (int j = 0; j < BF; ++j)
#pragma unroll
      for (int q = 0; q < 4; ++q) {
        int rr = tm + wr * WM + i * 16 + fg * 4 + q;
        int cc = tn + wc * WN + j * 16 + fr;
        Cz[(size_t)rr * N + cc] = acc[i][j][q];
      }
}

// ---------------- BatchNorm (train mode) ----------------
__global__ void bn_stats_red_kernel(const float* __restrict__ Yp, float* __restrict__ Yred,
                                    float* __restrict__ psum, float* __restrict__ psq,
                                    int Ncols, int rowsPer, int P, size_t pstride) {
  int c = blockIdx.x * blockDim.x + threadIdx.x;
  int r0 = blockIdx.y * rowsPer;
  float s = 0.f, ss = 0.f;
  for (int r = 0; r < rowsPer; ++r) {
    size_t idx = (size_t)(r0 + r) * Ncols + c;
    float v = Yp[idx];
    for (int p = 1; p < P; ++p) v += Yp[idx + (size_t)p * pstride];
    Yred[idx] = v;
    s += v;
    ss += v * v;
  }
  psum[(size_t)blockIdx.y * Ncols + c] = s;
  psq[(size_t)blockIdx.y * Ncols + c] = ss;
}

__global__ void bn_finalize_kernel(const float* __restrict__ psum, const float* __restrict__ psq,
                                   const float* __restrict__ g, const float* __restrict__ b,
                                   float* __restrict__ scale, float* __restrict__ shift,
                                   int Ncols, int P, float invM) {
  int c = blockIdx.x * blockDim.x + threadIdx.x;
  if (c >= Ncols) return;
  float s = 0.f, ss = 0.f;
  for (int p = 0; p < P; ++p) {
    s += psum[(size_t)p * Ncols + c];
    ss += psq[(size_t)p * Ncols + c];
  }
  float mean = s * invM;
  float var = ss * invM - mean * mean;
  float rstd = rsqrtf(var + 1e-5f);
  float sc = rstd * g[c];
  scale[c] = sc;
  shift[c] = b[c] - mean * sc;
}

__global__ void bn_apply_kernel(const float* __restrict__ Y, const float* __restrict__ scale,
                                const float* __restrict__ shift, unsigned short* __restrict__ X,
                                int NcolsMask, int total) {
  int i = blockIdx.x * blockDim.x + threadIdx.x;
  if (i >= total) return;
  int c = i & NcolsMask;
  float v = Y[i] * scale[c] + shift[c];
  v = fmaxf(v, 0.0f);
  X[i] = f2bf(v);
}

// ---------------- decode ----------------
// Y3 holds KSPLIT=4 partials of (2048 x 96)
__global__ void decode_kernel(const float* __restrict__ Y3, const float* __restrict__ pb,
                              const float* __restrict__ anchors, const int* __restrict__ aid,
                              float* __restrict__ out) {
  int i = blockIdx.x * blockDim.x + threadIdx.x;
  if (i >= 2048 * 94) return;
  int bn = i / 94;
  int ch = i - bn * 94;
  size_t idx = (size_t)bn * 96 + ch;
  float v = Y3[idx] + Y3[idx + 2048 * 96] + Y3[idx + 2 * 2048 * 96] + Y3[idx + 3 * 2048 * 96];
  v += pb[ch];
  float o = v;
  if (ch >= 4 && ch < 22) {
    int q = ch - 4;
    int d = q % 6;   // within-class: 0,1=yx 2,3=lw 4,5=zh
    if (d < 2) {
      float stride_px = (float)(8 << (aid[bn] / 3));
      o = anchors[(size_t)bn * 4 + d] + v * stride_px;
    } else if (d < 4) {
      float cl = fminf(fmaxf(v, -4.0f), 4.0f);
      o = anchors[(size_t)bn * 4 + d] * expf(cl);
    }
  }
  out[i] = o;
}

// ---------------- launch ----------------
extern "C" void kernel_launch(void* const* d_in, const int* in_sizes, int n_in,
                              void* d_out, int out_size, void* d_ws, size_t ws_size,
                              hipStream_t stream) {
  const float* feat_p3   = (const float*)d_in[0];
  const float* feat_p4   = (const float*)d_in[1];
  const float* feat_p5   = (const float*)d_in[2];
  const float* bbox2d    = (const float*)d_in[3];
  const float* anchors   = (const float*)d_in[4];
  const int*   anchor_id = (const int*)d_in[5];
  const float* fc1_w     = (const float*)d_in[6];
  // d_in[7] fc1_b: cancels through train-mode BN (mean subtraction) — unused
  const float* bn1_g     = (const float*)d_in[8];
  const float* bn1_b     = (const float*)d_in[9];
  const float* fc2_w     = (const float*)d_in[10];
  // d_in[11] fc2_b: cancels — unused
  const float* bn2_g     = (const float*)d_in[12];
  const float* bn2_b     = (const float*)d_in[13];
  const float* pred_w    = (const float*)d_in[14];
  const float* pred_b    = (const float*)d_in[15];
  float* out = (float*)d_out;

  const int M = 2048;          // B*N
  const int K1 = 12544;        // 256*7*7
  const int FC = 1024;

  char* ws = (char*)d_ws;
  auto alloc = [&](size_t bytes) -> char* {
    char* p = ws;
    ws += (bytes + 255) & ~(size_t)255;
    return p;
  };
  unsigned short* W1b  = (unsigned short*)alloc((size_t)FC * K1 * 2);
  unsigned short* W2b  = (unsigned short*)alloc((size_t)FC * FC * 2);
  unsigned short* W3b  = (unsigned short*)alloc((size_t)96 * FC * 2);
  unsigned short* X1   = (unsigned short*)alloc((size_t)M * K1 * 2);
  unsigned short* Wbuf = (unsigned short*)alloc((size_t)M * 13312 * 2);  // 26624 B/box
  int2*           rbas = (int2*)alloc((size_t)M * 8);
  float*          Yp   = (float*)alloc((size_t)4 * M * FC * 4);  // split-K partials
  float*          Yr   = (float*)alloc((size_t)M * FC * 4);      // reduced Y
  unsigned short* X2   = (unsigned short*)alloc((size_t)M * FC * 2);
  unsigned short* X3   = (unsigned short*)alloc((size_t)M * FC * 2);
  float*          Y3   = (float*)alloc((size_t)4 * M * 96 * 4);
  float*          ps   = (float*)alloc((size_t)16 * FC * 4);
  float*          pq   = (float*)alloc((size_t)16 * FC * 4);
  float*          sc1  = (float*)alloc((size_t)FC * 4);
  float*          sh1  = (float*)alloc((size_t)FC * 4);
  float*          sc2  = (float*)alloc((size_t)FC * 4);
  float*          sh2  = (float*)alloc((size_t)FC * 4);

  // weight conversions (must redo each call — no cross-call state allowed)
  {
    size_t n = (size_t)FC * K1;
    cvt_bf16_kernel<<<(unsigned)((n + 255) / 256), 256, 0, stream>>>(fc1_w, W1b, n);
  }
  {
    size_t n = (size_t)FC * FC;
    cvt_bf16_kernel<<<(unsigned)((n + 255) / 256), 256, 0, stream>>>(fc2_w, W2b, n);
  }
  cvt_pad_pred_kernel<<<(96 * 1024) / 256, 256, 0, stream>>>(pred_w, W3b);

  // ROI align: wgen (per-box separable weights) then per-box MFMA GEMM -> X1
  wgen_kernel<<<2048, 256, 0, stream>>>(bbox2d, anchor_id, Wbuf, rbas);
  roi_mm_kernel<<<dim3(2048, 8), 256, 0, stream>>>(feat_p3, feat_p4, feat_p5,
                                                   Wbuf, rbas, anchor_id, X1);

  // fc1: X1 (2048x12544) @ W1^T -> Yp (4 partials of 2048x1024)
  gemm_bt_swz<4><<<dim3(M / 128, FC / 128, 4), 256, 0, stream>>>(X1, W1b, Yp, M, FC, K1);

  // BN1: reduce partials + stats, finalize, apply+ReLU -> X2 bf16
  bn_stats_red_kernel<<<dim3(FC / 256, 16), 256, 0, stream>>>(Yp, Yr, ps, pq, FC, M / 16, 4, (size_t)M * FC);
  bn_finalize_kernel<<<FC / 256, 256, 0, stream>>>(ps, pq, bn1_g, bn1_b, sc1, sh1, FC, 16, 1.0f / M);
  bn_apply_kernel<<<(M * FC) / 256, 256, 0, stream>>>(Yr, sc1, sh1, X2, FC - 1, M * FC);

  // fc2: X2 @ W2^T -> Yp (2 partials)
  gemm_bt_swz<2><<<dim3(M / 128, FC / 128, 2), 256, 0, stream>>>(X2, W2b, Yp, M, FC, FC);

  // BN2 + ReLU -> X3 bf16
  bn_stats_red_kernel<<<dim3(FC / 256, 16), 256, 0, stream>>>(Yp, Yr, ps, pq, FC, M / 16, 2, (size_t)M * FC);
  bn_finalize_kernel<<<FC / 256, 256, 0, stream>>>(ps, pq, bn2_g, bn2_b, sc2, sh2, FC, 16, 1.0f / M);
  bn_apply_kernel<<<(M * FC) / 256, 256, 0, stream>>>(Yr, sc2, sh2, X3, FC - 1, M * FC);

  // pred head: X3 @ W3p^T -> Y3 (split-K=4 partials of 2048 x 96)
  gemm_bt_kernel<64, 96, 2, 2, 4><<<dim3(M / 64, 1, 4), 256, 0, stream>>>(X3, W3b, Y3, M, 96, FC);

  // decode -> out (2048 x 94)
  decode_kernel<<<(2048 * 94 + 255) / 256, 256, 0, stream>>>(Y3, pred_b, anchors, anchor_id, out);
}

// Round 7
// 303.547 us; speedup vs baseline: 1.7080x; 1.2558x over previous
//
#include <hip/hip_runtime.h>
#include <hip/hip_bf16.h>

typedef __attribute__((ext_vector_type(8))) short short8;
typedef __attribute__((ext_vector_type(4))) float floatx4;
typedef __attribute__((ext_vector_type(4))) unsigned short ushort4v;

#define DEVI __device__ __forceinline__

// ---------------- constants ----------------
// B=4, N=512, C_IN=256, RES=7, SR=2, FC_DIM=1024, OUT_CH=94
// M = B*N = 2048 rows, K1 = 256*7*7 = 12544

DEVI unsigned short f2bf(float v) {
  union { __hip_bfloat16 h; unsigned short u; } cv;
  cv.h = __float2bfloat16(v);
  return cv.u;
}
DEVI short f2bfs(float v) { return (short)f2bf(v); }

DEVI void gload16(const void* gptr, void* lptr) {
  __builtin_amdgcn_global_load_lds(
      (const __attribute__((address_space(1))) unsigned int*)gptr,
      (__attribute__((address_space(3))) unsigned int*)(unsigned long long)(uintptr_t)lptr,
      16, 0, 0);
}

// ---------------- weight conversion (vectorized: 4 floats -> 4 bf16 / thread) ----------------
__global__ void cvt_bf16x4_kernel(const float4* __restrict__ src,
                                  ushort4v* __restrict__ dst, size_t n4) {
  size_t i = (size_t)blockIdx.x * blockDim.x + threadIdx.x;
  if (i >= n4) return;
  float4 v = src[i];
  ushort4v o;
  o[0] = f2bf(v.x); o[1] = f2bf(v.y); o[2] = f2bf(v.z); o[3] = f2bf(v.w);
  dst[i] = o;
}

// pred_w (94x1024) -> padded (96x1024) bf16, rows 94..95 zero
__global__ void cvt_pad_pred_kernel(const float* __restrict__ src,
                                    unsigned short* __restrict__ dst) {
  int i = blockIdx.x * blockDim.x + threadIdx.x;
  if (i >= 96 * 1024) return;
  int row = i >> 10;
  dst[i] = (row < 94) ? f2bf(src[i]) : (unsigned short)0;
}

// ---------------- ROI align: W generation (per box) ----------------
__global__ __launch_bounds__(256) void wgen_kernel(
    const float* __restrict__ bbox, const int* __restrict__ aid,
    unsigned short* __restrict__ Wbuf, int2* __restrict__ rbase) {
  const int box = blockIdx.x;
  const int tid = threadIdx.x;
  __shared__ int sy0[14], sx0[14];
  __shared__ float sly[14], slx[14];
  __shared__ float wy[7][16], wx[7][16];

  const int lvl = aid[box] / 3;
  const int H = 64 >> lvl;
  const float scale = 0.125f / (float)(1 << lvl);

  if (tid < 28) {
    int s = tid;
    bool isY = s < 14;
    int k = isY ? s : s - 14;
    float lo = bbox[box * 4 + (isY ? 0 : 1)];
    float hi = bbox[box * 4 + (isY ? 2 : 3)];
    float t = lo * scale - 0.5f;
    float cell = (hi - lo) * scale * (1.0f / 7.0f);
    float pos = t + ((float)k + 0.5f) * 0.5f * cell;   // S=14 samples, SR=2
    pos = fminf(fmaxf(pos, 0.0f), (float)(H - 1));
    int i0 = (int)floorf(pos);
    if (i0 > H - 2) i0 = H - 2;        // fr=1 reproduces the clamp
    float fr = pos - (float)i0;
    if (isY) { sy0[k] = i0; sly[k] = fr; }
    else     { sx0[k] = i0; slx[k] = fr; }
  }
  __syncthreads();

  const int ryb = min(sy0[0], H - 16);   // grid is monotone -> sy0[0]/sx0[0] are minima
  const int rxb = min(sx0[0], H - 16);
  if (tid == 0) rbase[box] = make_int2(ryb, rxb);

  if (tid < 224) {
    int j = tid;
    bool isY = j < 112;
    int k2 = isY ? j : j - 112;
    int py = k2 >> 4, r = k2 & 15;
    int o0 = isY ? ryb : rxb;
    float acc = 0.f;
#pragma unroll
    for (int ss = 0; ss < 2; ++ss) {
      int s = 2 * py + ss;
      int rel = (isY ? sy0[s] : sx0[s]) - o0;
      float fr = isY ? sly[s] : slx[s];
      if (r == rel)     acc += 1.0f - fr;
      if (r == rel + 1) acc += fr;
    }
    if (isY) wy[py][r] = acc * 0.5f;
    else     wx[py][r] = acc * 0.5f;
  }
  __syncthreads();

  unsigned short* wb = Wbuf + (size_t)box * 13312;   // 26624 B per box
  for (int idx = tid; idx < 49 * 256; idx += 256) {
    int cell = idx >> 8, k = idx & 255;
    int r = k >> 4, c = k & 15;
    int py = (cell * 37) >> 8;   // cell/7 for 0..55
    int px = cell - py * 7;
    wb[cell * 264 + k] = f2bf(wy[py][r] * wx[px][c]);
  }
}

// ---------------- ROI align: per-box MFMA GEMM ----------------
__global__ __launch_bounds__(256) void roi_mm_kernel(
    const float* __restrict__ p3, const float* __restrict__ p4,
    const float* __restrict__ p5, const unsigned short* __restrict__ Wbuf,
    const int2* __restrict__ rbase, const int* __restrict__ aid,
    unsigned short* __restrict__ X) {
  constexpr int PS = 260;   // f32 per-channel stride
  constexpr int WS = 264;   // bf16 per-cell stride
  __shared__ float P[32 * PS];             // 33280 B
  __shared__ unsigned short W[64 * WS];    // 33792 B (rows >=51 uninit, masked)

  const int box = blockIdx.x;
  const int oct = blockIdx.y;              // channels oct*32 ..
  const int b = box >> 9;
  const int tid = threadIdx.x;
  const int lane = tid & 63, wid = tid >> 6;

  const int lvl = aid[box] / 3;
  const int H = 64 >> lvl;
  const int HH = H * H;
  const float* base = (lvl == 0) ? p3 : ((lvl == 1) ? p4 : p5);
  const int2 rb = rbase[box];
  const float* fb = base + ((size_t)b * 256 + oct * 32) * HH + rb.x * H + rb.y;

  // stage W: 1664 slots x 16B = 26624 B
  const unsigned short* wsrc = Wbuf + (size_t)box * 13312;
  for (int s = tid; s < 1664; s += 256)
    gload16(wsrc + s * 8, (unsigned short*)W + s * 8);

  // stage P: per wave-iteration one channel; lane l -> (row l>>2, col4 l&3)
  {
    const int r = lane >> 2, c4 = (lane & 3) * 4;
    const float* src0 = fb + r * H + c4;
#pragma unroll
    for (int it = 0; it < 8; ++it) {
      int ch = it * 4 + wid;
      gload16(src0 + (size_t)ch * HH, &P[ch * PS] + lane * 4);
    }
  }
  __syncthreads();

  // MFMA: wave -> ch-frag (wid>>1), cell-half (wid&1)
  const int fr = lane & 15, fg = lane >> 4;
  const int chf = wid >> 1;
  const int cellb = (wid & 1) * 32;

  floatx4 acc0 = (floatx4){0.f, 0.f, 0.f, 0.f};
  floatx4 acc1 = (floatx4){0.f, 0.f, 0.f, 0.f};

#pragma unroll
  for (int kk = 0; kk < 8; ++kk) {
    const float* ap = &P[(chf * 16 + fr) * PS + kk * 32 + fg * 8];
    floatx4 a0 = *(const floatx4*)ap;
    floatx4 a1 = *(const floatx4*)(ap + 4);
    short8 af;
    af[0] = f2bfs(a0[0]); af[1] = f2bfs(a0[1]); af[2] = f2bfs(a0[2]); af[3] = f2bfs(a0[3]);
    af[4] = f2bfs(a1[0]); af[5] = f2bfs(a1[1]); af[6] = f2bfs(a1[2]); af[7] = f2bfs(a1[3]);
    short8 b0 = *(const short8*)&W[(cellb + fr) * WS + kk * 32 + fg * 8];
    short8 b1 = *(const short8*)&W[(cellb + 16 + fr) * WS + kk * 32 + fg * 8];
    acc0 = __builtin_amdgcn_mfma_f32_16x16x32_bf16(af, b0, acc0, 0, 0, 0);
    acc1 = __builtin_amdgcn_mfma_f32_16x16x32_bf16(af, b1, acc1, 0, 0, 0);
  }

  unsigned short* xb = X + (size_t)box * 12544 + (size_t)(oct * 32 + chf * 16) * 49;
  {
    int cell = cellb + fr;
    if (cell < 49) {
#pragma unroll
      for (int q = 0; q < 4; ++q)
        xb[(fg * 4 + q) * 49 + cell] = f2bf(acc0[q]);
    }
    cell = cellb + 16 + fr;
    if (cell < 49) {
#pragma unroll
      for (int q = 0; q < 4; ++q)
        xb[(fg * 4 + q) * 49 + cell] = f2bf(acc1[q]);
    }
  }
}

// ---------------- GEMM v2: 128x128 tile, BK=64, T2 XOR-swizzle, split-K ----------------
template <int KSPLIT>
__global__ __launch_bounds__(256) void gemm_bt_swz(
    const unsigned short* __restrict__ A, const unsigned short* __restrict__ Bw,
    float* __restrict__ C, int M, int N, int K) {
  constexpr int BM = 128, BN = 128, BK = 64;
  __shared__ unsigned short As[BM * BK];   // 16 KB
  __shared__ unsigned short Bs[BN * BK];   // 16 KB

  const int tid = threadIdx.x;
  const int lane = tid & 63, wid = tid >> 6;
  const int wr = wid >> 1, wc = wid & 1;    // 2x2 waves, 64x64 each
  const int tm = blockIdx.x * BM, tn = blockIdx.y * BN;
  const int fr = lane & 15, fg = lane >> 4;

  const int kLen = K / KSPLIT;
  const int kTiles = kLen / BK;
  const int kBeg = blockIdx.z * kLen;
  float* Cz = C + (size_t)blockIdx.z * M * N;

  floatx4 acc[4][4];
#pragma unroll
  for (int i = 0; i < 4; ++i)
#pragma unroll
    for (int j = 0; j < 4; ++j)
      acc[i][j] = (floatx4){0.f, 0.f, 0.f, 0.f};

  for (int t = 0; t < kTiles; ++t) {
    const int k0 = kBeg + t * BK;
#pragma unroll
    for (int s = tid; s < BM * 8; s += 256) {
      int row = s >> 3, sl = s & 7;
      int slg = sl ^ (row & 7);
      gload16(&A[(size_t)(tm + row) * K + k0 + slg * 8], &As[s * 8]);
    }
#pragma unroll
    for (int s = tid; s < BN * 8; s += 256) {
      int row = s >> 3, sl = s & 7;
      int slg = sl ^ (row & 7);
      gload16(&Bw[(size_t)(tn + row) * K + k0 + slg * 8], &Bs[s * 8]);
    }
    __syncthreads();

#pragma unroll
    for (int kk = 0; kk < 2; ++kk) {
      short8 af[4], bf[4];
#pragma unroll
      for (int i = 0; i < 4; ++i) {
        int row = wr * 64 + i * 16 + fr;
        int sl = (kk * 4 + fg) ^ (row & 7);
        af[i] = *reinterpret_cast<const short8*>(&As[(row * 8 + sl) * 8]);
      }
#pragma unroll
      for (int j = 0; j < 4; ++j) {
        int row = wc * 64 + j * 16 + fr;
        int sl = (kk * 4 + fg) ^ (row & 7);
        bf[j] = *reinterpret_cast<const short8*>(&Bs[(row * 8 + sl) * 8]);
      }
#pragma unroll
      for (int i = 0; i < 4; ++i)
#pragma unroll
        for (int j = 0; j < 4; ++j)
          acc[i][j] = __builtin_amdgcn_mfma_f32_16x16x32_bf16(af[i], bf[j], acc[i][j], 0, 0, 0);
    }
    __syncthreads();
  }

#pragma unroll
  for (int i = 0; i < 4; ++i)
#pragma unroll
    for (int j = 0; j < 4; ++j)
#pragma unroll
      for (int q = 0; q < 4; ++q) {
        int rr = tm + wr * 64 + i * 16 + fg * 4 + q;
        int cc = tn + wc * 64 + j * 16 + fr;
        Cz[(size_t)rr * N + cc] = acc[i][j][q];
      }
}

// ---------------- old GEMM (pred head only) ----------------
template <int BM, int BN, int WAVES_M, int WAVES_N, int KSPLIT>
__global__ __launch_bounds__(256) void gemm_bt_kernel(
    const unsigned short* __restrict__ A, const unsigned short* __restrict__ Bw,
    float* __restrict__ C, int M, int N, int K) {
  constexpr int BK = 32;
  constexpr int WM = BM / WAVES_M, WN = BN / WAVES_N;
  constexpr int AF = WM / 16, BF = WN / 16;
  constexpr int ASLOT = BM * 4;
  constexpr int BSLOT = BN * 4;
  __shared__ unsigned short As[BM * BK];
  __shared__ unsigned short Bs[BN * BK];

  const int tid = threadIdx.x;
  const int lane = tid & 63, wid = tid >> 6;
  const int wr = wid / WAVES_N, wc = wid % WAVES_N;
  const int tm = blockIdx.x * BM, tn = blockIdx.y * BN;
  const int fr = lane & 15, fg = lane >> 4;

  const int kLen = K / KSPLIT;
  const int kBeg = blockIdx.z * kLen;
  float* Cz = C + (size_t)blockIdx.z * M * N;

  floatx4 acc[AF][BF];
#pragma unroll
  for (int i = 0; i < AF; ++i)
#pragma unroll
    for (int j = 0; j < BF; ++j)
      acc[i][j] = (floatx4){0.f, 0.f, 0.f, 0.f};

  for (int k0 = kBeg; k0 < kBeg + kLen; k0 += BK) {
#pragma unroll
    for (int s = tid; s < ASLOT; s += 256) {
      int row = s >> 2, kb = (s & 3) << 3;
      gload16(&A[(size_t)(tm + row) * K + k0 + kb], &As[s * 8]);
    }
#pragma unroll
    for (int s = tid; s < BSLOT; s += 256) {
      int row = s >> 2, kb = (s & 3) << 3;
      gload16(&Bw[(size_t)(tn + row) * K + k0 + kb], &Bs[s * 8]);
    }
    __syncthreads();

    short8 af[AF], bfv[BF];
#pragma unroll
    for (int i = 0; i < AF; ++i)
      af[i] = *reinterpret_cast<const short8*>(&As[(wr * WM + i * 16 + fr) * BK + fg * 8]);
#pragma unroll
    for (int j = 0; j < BF; ++j)
      bfv[j] = *reinterpret_cast<const short8*>(&Bs[(wc * WN + j * 16 + fr) * BK + fg * 8]);
#pragma unroll
    for (int i = 0; i < AF; ++i)
#pragma unroll
      for (int j = 0; j < BF; ++j)
        acc[i][j] = __builtin_amdgcn_mfma_f32_16x16x32_bf16(af[i], bfv[j], acc[i][j], 0, 0, 0);
    __syncthreads();
  }

#pragma unroll
  for (int i = 0; i < AF; ++i)
#pragma unroll
    for (int j = 0; j < BF; ++j)
#pragma unroll
      for (int q = 0; q < 4; ++q) {
        int rr = tm + wr * WM + i * 16 + fg * 4 + q;
        int cc = tn + wc * WN + j * 16 + fr;
        Cz[(size_t)rr * N + cc] = acc[i][j][q];
      }
}

// ---------------- BatchNorm (train mode) ----------------
// pass 1: reduce split-K partials + per-rowgroup stats.
// grid (Ncols/256, 128) = 512 blocks; 16 rows per thread.
__global__ void bn_stats_red_kernel(const float* __restrict__ Yp, float* __restrict__ Yred,
                                    float* __restrict__ psum, float* __restrict__ psq,
                                    int Ncols, int rowsPer, int P, size_t pstride) {
  int c = blockIdx.x * blockDim.x + threadIdx.x;
  int r0 = blockIdx.y * rowsPer;
  float s = 0.f, ss = 0.f;
  for (int r = 0; r < rowsPer; ++r) {
    size_t idx = (size_t)(r0 + r) * Ncols + c;
    float v = Yp[idx];
    for (int p = 1; p < P; ++p) v += Yp[idx + (size_t)p * pstride];
    Yred[idx] = v;
    s += v;
    ss += v * v;
  }
  psum[(size_t)blockIdx.y * Ncols + c] = s;
  psq[(size_t)blockIdx.y * Ncols + c] = ss;
}

__global__ void bn_finalize_kernel(const float* __restrict__ psum, const float* __restrict__ psq,
                                   const float* __restrict__ g, const float* __restrict__ b,
                                   float* __restrict__ scale, float* __restrict__ shift,
                                   int Ncols, int P, float invM) {
  int c = blockIdx.x * blockDim.x + threadIdx.x;
  if (c >= Ncols) return;
  float s = 0.f, ss = 0.f;
  for (int p = 0; p < P; ++p) {
    s += psum[(size_t)p * Ncols + c];
    ss += psq[(size_t)p * Ncols + c];
  }
  float mean = s * invM;
  float var = ss * invM - mean * mean;
  float rstd = rsqrtf(var + 1e-5f);
  float sc = rstd * g[c];
  scale[c] = sc;
  shift[c] = b[c] - mean * sc;
}

// pass 2: apply, vectorized float4 -> 4x bf16 (FC divisible by 4)
__global__ void bn_apply4_kernel(const float4* __restrict__ Y, const float* __restrict__ scale,
                                 const float* __restrict__ shift, ushort4v* __restrict__ X,
                                 int colGroupsMask, int total4) {
  int i = blockIdx.x * blockDim.x + threadIdx.x;
  if (i >= total4) return;
  int c0 = (i & colGroupsMask) * 4;
  float4 v = Y[i];
  ushort4v o;
  o[0] = f2bf(fmaxf(v.x * scale[c0 + 0] + shift[c0 + 0], 0.0f));
  o[1] = f2bf(fmaxf(v.y * scale[c0 + 1] + shift[c0 + 1], 0.0f));
  o[2] = f2bf(fmaxf(v.z * scale[c0 + 2] + shift[c0 + 2], 0.0f));
  o[3] = f2bf(fmaxf(v.w * scale[c0 + 3] + shift[c0 + 3], 0.0f));
  X[i] = o;
}

// ---------------- decode ----------------
// Y3 holds KSPLIT=4 partials of (2048 x 96)
__global__ void decode_kernel(const float* __restrict__ Y3, const float* __restrict__ pb,
                              const float* __restrict__ anchors, const int* __restrict__ aid,
                              float* __restrict__ out) {
  int i = blockIdx.x * blockDim.x + threadIdx.x;
  if (i >= 2048 * 94) return;
  int bn = i / 94;
  int ch = i - bn * 94;
  size_t idx = (size_t)bn * 96 + ch;
  float v = Y3[idx] + Y3[idx + 2048 * 96] + Y3[idx + 2 * 2048 * 96] + Y3[idx + 3 * 2048 * 96];
  v += pb[ch];
  float o = v;
  if (ch >= 4 && ch < 22) {
    int q = ch - 4;
    int d = q % 6;   // within-class: 0,1=yx 2,3=lw 4,5=zh
    if (d < 2) {
      float stride_px = (float)(8 << (aid[bn] / 3));
      o = anchors[(size_t)bn * 4 + d] + v * stride_px;
    } else if (d < 4) {
      float cl = fminf(fmaxf(v, -4.0f), 4.0f);
      o = anchors[(size_t)bn * 4 + d] * expf(cl);
    }
  }
  out[i] = o;
}

// ---------------- launch ----------------
extern "C" void kernel_launch(void* const* d_in, const int* in_sizes, int n_in,
                              void* d_out, int out_size, void* d_ws, size_t ws_size,
                              hipStream_t stream) {
  const float* feat_p3   = (const float*)d_in[0];
  const float* feat_p4   = (const float*)d_in[1];
  const float* feat_p5   = (const float*)d_in[2];
  const float* bbox2d    = (const float*)d_in[3];
  const float* anchors   = (const float*)d_in[4];
  const int*   anchor_id = (const int*)d_in[5];
  const float* fc1_w     = (const float*)d_in[6];
  // d_in[7] fc1_b: cancels through train-mode BN (mean subtraction) — unused
  const float* bn1_g     = (const float*)d_in[8];
  const float* bn1_b     = (const float*)d_in[9];
  const float* fc2_w     = (const float*)d_in[10];
  // d_in[11] fc2_b: cancels — unused
  const float* bn2_g     = (const float*)d_in[12];
  const float* bn2_b     = (const float*)d_in[13];
  const float* pred_w    = (const float*)d_in[14];
  const float* pred_b    = (const float*)d_in[15];
  float* out = (float*)d_out;

  const int M = 2048;          // B*N
  const int K1 = 12544;        // 256*7*7
  const int FC = 1024;
  const int RG = 128;          // BN stats row-groups

  char* ws = (char*)d_ws;
  auto alloc = [&](size_t bytes) -> char* {
    char* p = ws;
    ws += (bytes + 255) & ~(size_t)255;
    return p;
  };
  unsigned short* W1b  = (unsigned short*)alloc((size_t)FC * K1 * 2);
  unsigned short* W2b  = (unsigned short*)alloc((size_t)FC * FC * 2);
  unsigned short* W3b  = (unsigned short*)alloc((size_t)96 * FC * 2);
  unsigned short* X1   = (unsigned short*)alloc((size_t)M * K1 * 2);
  unsigned short* Wbuf = (unsigned short*)alloc((size_t)M * 13312 * 2);  // 26624 B/box
  int2*           rbas = (int2*)alloc((size_t)M * 8);
  float*          Yp   = (float*)alloc((size_t)4 * M * FC * 4);  // split-K partials
  float*          Yr   = (float*)alloc((size_t)M * FC * 4);      // reduced Y
  unsigned short* X2   = (unsigned short*)alloc((size_t)M * FC * 2);
  unsigned short* X3   = (unsigned short*)alloc((size_t)M * FC * 2);
  float*          Y3   = (float*)alloc((size_t)4 * M * 96 * 4);
  float*          ps   = (float*)alloc((size_t)RG * FC * 4);
  float*          pq   = (float*)alloc((size_t)RG * FC * 4);
  float*          sc1  = (float*)alloc((size_t)FC * 4);
  float*          sh1  = (float*)alloc((size_t)FC * 4);
  float*          sc2  = (float*)alloc((size_t)FC * 4);
  float*          sh2  = (float*)alloc((size_t)FC * 4);

  // weight conversions (must redo each call — no cross-call state allowed)
  {
    size_t n4 = (size_t)FC * K1 / 4;
    cvt_bf16x4_kernel<<<(unsigned)((n4 + 255) / 256), 256, 0, stream>>>(
        (const float4*)fc1_w, (ushort4v*)W1b, n4);
  }
  {
    size_t n4 = (size_t)FC * FC / 4;
    cvt_bf16x4_kernel<<<(unsigned)((n4 + 255) / 256), 256, 0, stream>>>(
        (const float4*)fc2_w, (ushort4v*)W2b, n4);
  }
  cvt_pad_pred_kernel<<<(96 * 1024) / 256, 256, 0, stream>>>(pred_w, W3b);

  // ROI align: wgen (per-box separable weights) then per-box MFMA GEMM -> X1
  wgen_kernel<<<2048, 256, 0, stream>>>(bbox2d, anchor_id, Wbuf, rbas);
  roi_mm_kernel<<<dim3(2048, 8), 256, 0, stream>>>(feat_p3, feat_p4, feat_p5,
                                                   Wbuf, rbas, anchor_id, X1);

  // fc1: X1 (2048x12544) @ W1^T -> Yp (4 partials of 2048x1024)
  gemm_bt_swz<4><<<dim3(M / 128, FC / 128, 4), 256, 0, stream>>>(X1, W1b, Yp, M, FC, K1);

  // BN1: reduce partials + stats (512 blocks), finalize, apply+ReLU -> X2 bf16
  bn_stats_red_kernel<<<dim3(FC / 256, RG), 256, 0, stream>>>(Yp, Yr, ps, pq, FC, M / RG, 4, (size_t)M * FC);
  bn_finalize_kernel<<<FC / 256, 256, 0, stream>>>(ps, pq, bn1_g, bn1_b, sc1, sh1, FC, RG, 1.0f / M);
  bn_apply4_kernel<<<(M * FC / 4) / 256, 256, 0, stream>>>(
      (const float4*)Yr, sc1, sh1, (ushort4v*)X2, FC / 4 - 1, M * FC / 4);

  // fc2: X2 @ W2^T -> Yp (2 partials)
  gemm_bt_swz<2><<<dim3(M / 128, FC / 128, 2), 256, 0, stream>>>(X2, W2b, Yp, M, FC, FC);

  // BN2 + ReLU -> X3 bf16
  bn_stats_red_kernel<<<dim3(FC / 256, RG), 256, 0, stream>>>(Yp, Yr, ps, pq, FC, M / RG, 2, (size_t)M * FC);
  bn_finalize_kernel<<<FC / 256, 256, 0, stream>>>(ps, pq, bn2_g, bn2_b, sc2, sh2, FC, RG, 1.0f / M);
  bn_apply4_kernel<<<(M * FC / 4) / 256, 256, 0, stream>>>(
      (const float4*)Yr, sc2, sh2, (ushort4v*)X3, FC / 4 - 1, M * FC / 4);

  // pred head: X3 @ W3p^T -> Y3 (split-K=4 partials of 2048 x 96)
  gemm_bt_kernel<64, 96, 2, 2, 4><<<dim3(M / 64, 1, 4), 256, 0, stream>>>(X3, W3b, Y3, M, 96, FC);

  // decode -> out (2048 x 94)
  decode_kernel<<<(2048 * 94 + 255) / 256, 256, 0, stream>>>(Y3, pred_b, anchors, anchor_id, out);
}

// Round 8
// 256.455 us; speedup vs baseline: 2.0217x; 1.1836x over previous
//
#include <hip/hip_runtime.h>
#include <hip/hip_bf16.h>

typedef __attribute__((ext_vector_type(8))) short short8;
typedef __attribute__((ext_vector_type(4))) float floatx4;
typedef __attribute__((ext_vector_type(4))) unsigned short ushort4v;

#define DEVI __device__ __forceinline__

// ---------------- constants ----------------
// B=4, N=512, C_IN=256, RES=7, SR=2, FC_DIM=1024, OUT_CH=94
// M = B*N = 2048 rows, K1 = 256*7*7 = 12544

DEVI unsigned short f2bf(float v) {
  union { __hip_bfloat16 h; unsigned short u; } cv;
  cv.h = __float2bfloat16(v);
  return cv.u;
}
DEVI short f2bfs(float v) { return (short)f2bf(v); }

DEVI void gload16(const void* gptr, void* lptr) {
  __builtin_amdgcn_global_load_lds(
      (const __attribute__((address_space(1))) unsigned int*)gptr,
      (__attribute__((address_space(3))) unsigned int*)(unsigned long long)(uintptr_t)lptr,
      16, 0, 0);
}

// ---------------- weight conversion (vectorized: 4 floats -> 4 bf16 / thread) ----------------
__global__ void cvt_bf16x4_kernel(const float4* __restrict__ src,
                                  ushort4v* __restrict__ dst, size_t n4) {
  size_t i = (size_t)blockIdx.x * blockDim.x + threadIdx.x;
  if (i >= n4) return;
  float4 v = src[i];
  ushort4v o;
  o[0] = f2bf(v.x); o[1] = f2bf(v.y); o[2] = f2bf(v.z); o[3] = f2bf(v.w);
  dst[i] = o;
}

// pred_w (94x1024) -> padded (96x1024) bf16, rows 94..95 zero
__global__ void cvt_pad_pred_kernel(const float* __restrict__ src,
                                    unsigned short* __restrict__ dst) {
  int i = blockIdx.x * blockDim.x + threadIdx.x;
  if (i >= 96 * 1024) return;
  int row = i >> 10;
  dst[i] = (row < 94) ? f2bf(src[i]) : (unsigned short)0;
}

// ---------------- ROI align: fused per-box MFMA GEMM, W on-the-fly ----------------
// Out[ch][cell] = sum_{r,c} P[ch][r*16+c] * wy[py][r] * wx[px][c]  (separable pooled
// bilinear weights). B-fragments are built in registers from wy/wx each k-step —
// no W tile in LDS, no W global traffic. grid (2048 boxes, 8 channel-octets of 32).
__global__ __launch_bounds__(256) void roi_mm2_kernel(
    const float* __restrict__ p3, const float* __restrict__ p4,
    const float* __restrict__ p5, const float* __restrict__ bbox,
    const int* __restrict__ aid, unsigned short* __restrict__ X) {
  constexpr int PS = 260;   // f32 per-channel stride (16B-aligned base per channel)
  __shared__ float P[32 * PS];          // 33280 B
  __shared__ float wyx[238];            // wy [7][17] @0, wx [7][17] @119
  __shared__ int sy0[14], sx0[14];
  __shared__ float sly[14], slx[14];

  const int box = blockIdx.x;
  const int oct = blockIdx.y;              // channels oct*32 ..
  const int b = box >> 9;
  const int tid = threadIdx.x;
  const int lane = tid & 63, wid = tid >> 6;

  const int lvl = aid[box] / 3;
  const int H = 64 >> lvl;
  const int HH = H * H;
  const float* base = (lvl == 0) ? p3 : ((lvl == 1) ? p4 : p5);
  const float scale = 0.125f / (float)(1 << lvl);

  // ---- phase A: sample grid ----
  if (tid < 28) {
    int s = tid;
    bool isY = s < 14;
    int k = isY ? s : s - 14;
    float lo = bbox[box * 4 + (isY ? 0 : 1)];
    float hi = bbox[box * 4 + (isY ? 2 : 3)];
    float t = lo * scale - 0.5f;
    float cell = (hi - lo) * scale * (1.0f / 7.0f);
    float pos = t + ((float)k + 0.5f) * 0.5f * cell;   // S=14 samples, SR=2
    pos = fminf(fmaxf(pos, 0.0f), (float)(H - 1));
    int i0 = (int)floorf(pos);
    if (i0 > H - 2) i0 = H - 2;        // fr=1 reproduces the clamp
    float fr = pos - (float)i0;
    if (isY) { sy0[k] = i0; sly[k] = fr; }
    else     { sx0[k] = i0; slx[k] = fr; }
  }
  __syncthreads();

  const int ryb = min(sy0[0], H - 16);   // monotone grid -> sy0[0]/sx0[0] are minima
  const int rxb = min(sx0[0], H - 16);
  const float* fb = base + ((size_t)b * 256 + oct * 32) * HH + ryb * H + rxb;

  // ---- phase B1: separable pooled weights wy[7][16], wx[7][16] (stride 17) ----
  if (tid < 224) {
    int j = tid;
    bool isY = j < 112;
    int k2 = isY ? j : j - 112;
    int py = k2 >> 4, r = k2 & 15;
    int o0 = isY ? ryb : rxb;
    float acc = 0.f;
#pragma unroll
    for (int ss = 0; ss < 2; ++ss) {
      int s = 2 * py + ss;
      int rel = (isY ? sy0[s] : sx0[s]) - o0;
      float fr = isY ? sly[s] : slx[s];
      if (r == rel)     acc += 1.0f - fr;
      if (r == rel + 1) acc += fr;
    }
    wyx[(isY ? 0 : 119) + py * 17 + r] = acc * 0.5f;
  }

  // ---- phase B2: stage P via global_load_lds (1 wave-op = 1 channel's 1KB patch) ----
  {
    const int r = lane >> 2, c4 = (lane & 3) * 4;
    const float* src0 = fb + r * H + c4;
#pragma unroll
    for (int it = 0; it < 8; ++it) {
      int ch = it * 4 + wid;
      gload16(src0 + (size_t)ch * HH, &P[ch * PS] + lane * 4);
    }
  }
  __syncthreads();

  // ---- phase C: MFMA, B-fragments on the fly ----
  const int fr = lane & 15, fg = lane >> 4;
  const int chf = wid >> 1;                // 0..1 (16-ch fragment)
  const int cellb = (wid & 1) * 32;        // cell half
  const int cell0 = cellb + fr;            // <= 47, always valid
  const int cell1 = cellb + 16 + fr;       // may be >= 49 (masked at store)
  const int py0 = (cell0 * 37) >> 8, px0 = cell0 - py0 * 7;   // ==/7, %7 for 0..63
  const int py1 = (cell1 * 37) >> 8, px1 = cell1 - py1 * 7;
  const float* wyB = wyx;                  // py1 up to 9 reads into wx region: garbage, masked
  const float* wxB = wyx + 119;

  floatx4 acc0 = (floatx4){0.f, 0.f, 0.f, 0.f};
  floatx4 acc1 = (floatx4){0.f, 0.f, 0.f, 0.f};

#pragma unroll
  for (int kk = 0; kk < 8; ++kk) {
    const float* ap = &P[(chf * 16 + fr) * PS + kk * 32 + fg * 8];
    floatx4 a0 = *(const floatx4*)ap;
    floatx4 a1 = *(const floatx4*)(ap + 4);
    short8 af;
    af[0] = f2bfs(a0[0]); af[1] = f2bfs(a0[1]); af[2] = f2bfs(a0[2]); af[3] = f2bfs(a0[3]);
    af[4] = f2bfs(a1[0]); af[5] = f2bfs(a1[1]); af[6] = f2bfs(a1[2]); af[7] = f2bfs(a1[3]);

    const int r = 2 * kk + (fg >> 1);      // k-row within patch
    const int c0 = (fg & 1) * 8;           // k-col base
    const float w0 = wyB[py0 * 17 + r];
    const float w1 = wyB[py1 * 17 + r];
    const float* x0 = &wxB[px0 * 17 + c0];
    const float* x1 = &wxB[px1 * 17 + c0];
    short8 b0, b1;
#pragma unroll
    for (int e = 0; e < 8; ++e) {
      b0[e] = f2bfs(w0 * x0[e]);
      b1[e] = f2bfs(w1 * x1[e]);
    }
    acc0 = __builtin_amdgcn_mfma_f32_16x16x32_bf16(af, b0, acc0, 0, 0, 0);
    acc1 = __builtin_amdgcn_mfma_f32_16x16x32_bf16(af, b1, acc1, 0, 0, 0);
  }

  unsigned short* xb = X + (size_t)box * 12544 + (size_t)(oct * 32 + chf * 16) * 49;
#pragma unroll
  for (int q = 0; q < 4; ++q)
    xb[(fg * 4 + q) * 49 + cell0] = f2bf(acc0[q]);
  if (cell1 < 49) {
#pragma unroll
    for (int q = 0; q < 4; ++q)
      xb[(fg * 4 + q) * 49 + cell1] = f2bf(acc1[q]);
  }
}

// ---------------- GEMM v2: 128x128 tile, BK=64, T2 XOR-swizzle, split-K ----------------
template <int KSPLIT>
__global__ __launch_bounds__(256) void gemm_bt_swz(
    const unsigned short* __restrict__ A, const unsigned short* __restrict__ Bw,
    float* __restrict__ C, int M, int N, int K) {
  constexpr int BM = 128, BN = 128, BK = 64;
  __shared__ unsigned short As[BM * BK];   // 16 KB
  __shared__ unsigned short Bs[BN * BK];   // 16 KB

  const int tid = threadIdx.x;
  const int lane = tid & 63, wid = tid >> 6;
  const int wr = wid >> 1, wc = wid & 1;    // 2x2 waves, 64x64 each
  const int tm = blockIdx.x * BM, tn = blockIdx.y * BN;
  const int fr = lane & 15, fg = lane >> 4;

  const int kLen = K / KSPLIT;
  const int kTiles = kLen / BK;
  const int kBeg = blockIdx.z * kLen;
  float* Cz = C + (size_t)blockIdx.z * M * N;

  floatx4 acc[4][4];
#pragma unroll
  for (int i = 0; i < 4; ++i)
#pragma unroll
    for (int j = 0; j < 4; ++j)
      acc[i][j] = (floatx4){0.f, 0.f, 0.f, 0.f};

  for (int t = 0; t < kTiles; ++t) {
    const int k0 = kBeg + t * BK;
#pragma unroll
    for (int s = tid; s < BM * 8; s += 256) {
      int row = s >> 3, sl = s & 7;
      int slg = sl ^ (row & 7);
      gload16(&A[(size_t)(tm + row) * K + k0 + slg * 8], &As[s * 8]);
    }
#pragma unroll
    for (int s = tid; s < BN * 8; s += 256) {
      int row = s >> 3, sl = s & 7;
      int slg = sl ^ (row & 7);
      gload16(&Bw[(size_t)(tn + row) * K + k0 + slg * 8], &Bs[s * 8]);
    }
    __syncthreads();

#pragma unroll
    for (int kk = 0; kk < 2; ++kk) {
      short8 af[4], bf[4];
#pragma unroll
      for (int i = 0; i < 4; ++i) {
        int row = wr * 64 + i * 16 + fr;
        int sl = (kk * 4 + fg) ^ (row & 7);
        af[i] = *reinterpret_cast<const short8*>(&As[(row * 8 + sl) * 8]);
      }
#pragma unroll
      for (int j = 0; j < 4; ++j) {
        int row = wc * 64 + j * 16 + fr;
        int sl = (kk * 4 + fg) ^ (row & 7);
        bf[j] = *reinterpret_cast<const short8*>(&Bs[(row * 8 + sl) * 8]);
      }
#pragma unroll
      for (int i = 0; i < 4; ++i)
#pragma unroll
        for (int j = 0; j < 4; ++j)
          acc[i][j] = __builtin_amdgcn_mfma_f32_16x16x32_bf16(af[i], bf[j], acc[i][j], 0, 0, 0);
    }
    __syncthreads();
  }

#pragma unroll
  for (int i = 0; i < 4; ++i)
#pragma unroll
    for (int j = 0; j < 4; ++j)
#pragma unroll
      for (int q = 0; q < 4; ++q) {
        int rr = tm + wr * 64 + i * 16 + fg * 4 + q;
        int cc = tn + wc * 64 + j * 16 + fr;
        Cz[(size_t)rr * N + cc] = acc[i][j][q];
      }
}

// ---------------- old GEMM (pred head only) ----------------
template <int BM, int BN, int WAVES_M, int WAVES_N, int KSPLIT>
__global__ __launch_bounds__(256) void gemm_bt_kernel(
    const unsigned short* __restrict__ A, const unsigned short* __restrict__ Bw,
    float* __restrict__ C, int M, int N, int K) {
  constexpr int BK = 32;
  constexpr int WM = BM / WAVES_M, WN = BN / WAVES_N;
  constexpr int AF = WM / 16, BF = WN / 16;
  constexpr int ASLOT = BM * 4;
  constexpr int BSLOT = BN * 4;
  __shared__ unsigned short As[BM * BK];
  __shared__ unsigned short Bs[BN * BK];

  const int tid = threadIdx.x;
  const int lane = tid & 63, wid = tid >> 6;
  const int wr = wid / WAVES_N, wc = wid % WAVES_N;
  const int tm = blockIdx.x * BM, tn = blockIdx.y * BN;
  const int fr = lane & 15, fg = lane >> 4;

  const int kLen = K / KSPLIT;
  const int kBeg = blockIdx.z * kLen;
  float* Cz = C + (size_t)blockIdx.z * M * N;

  floatx4 acc[AF][BF];
#pragma unroll
  for (int i = 0; i < AF; ++i)
#pragma unroll
    for (int j = 0; j < BF; ++j)
      acc[i][j] = (floatx4){0.f, 0.f, 0.f, 0.f};

  for (int k0 = kBeg; k0 < kBeg + kLen; k0 += BK) {
#pragma unroll
    for (int s = tid; s < ASLOT; s += 256) {
      int row = s >> 2, kb = (s & 3) << 3;
      gload16(&A[(size_t)(tm + row) * K + k0 + kb], &As[s * 8]);
    }
#pragma unroll
    for (int s = tid; s < BSLOT; s += 256) {
      int row = s >> 2, kb = (s & 3) << 3;
      gload16(&Bw[(size_t)(tn + row) * K + k0 + kb], &Bs[s * 8]);
    }
    __syncthreads();

    short8 af[AF], bfv[BF];
#pragma unroll
    for (int i = 0; i < AF; ++i)
      af[i] = *reinterpret_cast<const short8*>(&As[(wr * WM + i * 16 + fr) * BK + fg * 8]);
#pragma unroll
    for (int j = 0; j < BF; ++j)
      bfv[j] = *reinterpret_cast<const short8*>(&Bs[(wc * WN + j * 16 + fr) * BK + fg * 8]);
#pragma unroll
    for (int i = 0; i < AF; ++i)
#pragma unroll
      for (int j = 0; j < BF; ++j)
        acc[i][j] = __builtin_amdgcn_mfma_f32_16x16x32_bf16(af[i], bfv[j], acc[i][j], 0, 0, 0);
    __syncthreads();
  }

#pragma unroll
  for (int i = 0; i < AF; ++i)
#pragma unroll
    for (int j = 0; j < BF; ++j)
#pragma unroll
      for (int q = 0; q < 4; ++q) {
        int rr = tm + wr * WM + i * 16 + fg * 4 + q;
        int cc = tn + wc * WN + j * 16 + fr;
        Cz[(size_t)rr * N + cc] = acc[i][j][q];
      }
}

// ---------------- BatchNorm (train mode) ----------------
// pass 1: reduce split-K partials + per-rowgroup stats. grid (Ncols/256, 128).
__global__ void bn_stats_red_kernel(const float* __restrict__ Yp, float* __restrict__ Yred,
                                    float* __restrict__ psum, float* __restrict__ psq,
                                    int Ncols, int rowsPer, int P, size_t pstride) {
  int c = blockIdx.x * blockDim.x + threadIdx.x;
  int r0 = blockIdx.y * rowsPer;
  float s = 0.f, ss = 0.f;
  for (int r = 0; r < rowsPer; ++r) {
    size_t idx = (size_t)(r0 + r) * Ncols + c;
    float v = Yp[idx];
    for (int p = 1; p < P; ++p) v += Yp[idx + (size_t)p * pstride];
    Yred[idx] = v;
    s += v;
    ss += v * v;
  }
  psum[(size_t)blockIdx.y * Ncols + c] = s;
  psq[(size_t)blockIdx.y * Ncols + c] = ss;
}

__global__ void bn_finalize_kernel(const float* __restrict__ psum, const float* __restrict__ psq,
                                   const float* __restrict__ g, const float* __restrict__ b,
                                   float* __restrict__ scale, float* __restrict__ shift,
                                   int Ncols, int P, float invM) {
  int c = blockIdx.x * blockDim.x + threadIdx.x;
  if (c >= Ncols) return;
  float s = 0.f, ss = 0.f;
  for (int p = 0; p < P; ++p) {
    s += psum[(size_t)p * Ncols + c];
    ss += psq[(size_t)p * Ncols + c];
  }
  float mean = s * invM;
  float var = ss * invM - mean * mean;
  float rstd = rsqrtf(var + 1e-5f);
  float sc = rstd * g[c];
  scale[c] = sc;
  shift[c] = b[c] - mean * sc;
}

// pass 2: apply, vectorized float4 -> 4x bf16 (FC divisible by 4)
__global__ void bn_apply4_kernel(const float4* __restrict__ Y, const float* __restrict__ scale,
                                 const float* __restrict__ shift, ushort4v* __restrict__ X,
                                 int colGroupsMask, int total4) {
  int i = blockIdx.x * blockDim.x + threadIdx.x;
  if (i >= total4) return;
  int c0 = (i & colGroupsMask) * 4;
  float4 v = Y[i];
  ushort4v o;
  o[0] = f2bf(fmaxf(v.x * scale[c0 + 0] + shift[c0 + 0], 0.0f));
  o[1] = f2bf(fmaxf(v.y * scale[c0 + 1] + shift[c0 + 1], 0.0f));
  o[2] = f2bf(fmaxf(v.z * scale[c0 + 2] + shift[c0 + 2], 0.0f));
  o[3] = f2bf(fmaxf(v.w * scale[c0 + 3] + shift[c0 + 3], 0.0f));
  X[i] = o;
}

// ---------------- decode ----------------
// Y3 holds KSPLIT=4 partials of (2048 x 96)
__global__ void decode_kernel(const float* __restrict__ Y3, const float* __restrict__ pb,
                              const float* __restrict__ anchors, const int* __restrict__ aid,
                              float* __restrict__ out) {
  int i = blockIdx.x * blockDim.x + threadIdx.x;
  if (i >= 2048 * 94) return;
  int bn = i / 94;
  int ch = i - bn * 94;
  size_t idx = (size_t)bn * 96 + ch;
  float v = Y3[idx] + Y3[idx + 2048 * 96] + Y3[idx + 2 * 2048 * 96] + Y3[idx + 3 * 2048 * 96];
  v += pb[ch];
  float o = v;
  if (ch >= 4 && ch < 22) {
    int q = ch - 4;
    int d = q % 6;   // within-class: 0,1=yx 2,3=lw 4,5=zh
    if (d < 2) {
      float stride_px = (float)(8 << (aid[bn] / 3));
      o = anchors[(size_t)bn * 4 + d] + v * stride_px;
    } else if (d < 4) {
      float cl = fminf(fmaxf(v, -4.0f), 4.0f);
      o = anchors[(size_t)bn * 4 + d] * expf(cl);
    }
  }
  out[i] = o;
}

// ---------------- launch ----------------
extern "C" void kernel_launch(void* const* d_in, const int* in_sizes, int n_in,
                              void* d_out, int out_size, void* d_ws, size_t ws_size,
                              hipStream_t stream) {
  const float* feat_p3   = (const float*)d_in[0];
  const float* feat_p4   = (const float*)d_in[1];
  const float* feat_p5   = (const float*)d_in[2];
  const float* bbox2d    = (const float*)d_in[3];
  const float* anchors   = (const float*)d_in[4];
  const int*   anchor_id = (const int*)d_in[5];
  const float* fc1_w     = (const float*)d_in[6];
  // d_in[7] fc1_b: cancels through train-mode BN (mean subtraction) — unused
  const float* bn1_g     = (const float*)d_in[8];
  const float* bn1_b     = (const float*)d_in[9];
  const float* fc2_w     = (const float*)d_in[10];
  // d_in[11] fc2_b: cancels — unused
  const float* bn2_g     = (const float*)d_in[12];
  const float* bn2_b     = (const float*)d_in[13];
  const float* pred_w    = (const float*)d_in[14];
  const float* pred_b    = (const float*)d_in[15];
  float* out = (float*)d_out;

  const int M = 2048;          // B*N
  const int K1 = 12544;        // 256*7*7
  const int FC = 1024;
  const int RG = 128;          // BN stats row-groups

  char* ws = (char*)d_ws;
  auto alloc = [&](size_t bytes) -> char* {
    char* p = ws;
    ws += (bytes + 255) & ~(size_t)255;
    return p;
  };
  unsigned short* W1b  = (unsigned short*)alloc((size_t)FC * K1 * 2);
  unsigned short* W2b  = (unsigned short*)alloc((size_t)FC * FC * 2);
  unsigned short* W3b  = (unsigned short*)alloc((size_t)96 * FC * 2);
  unsigned short* X1   = (unsigned short*)alloc((size_t)M * K1 * 2);
  float*          Yp   = (float*)alloc((size_t)4 * M * FC * 4);  // split-K partials
  float*          Yr   = (float*)alloc((size_t)M * FC * 4);      // reduced Y
  unsigned short* X2   = (unsigned short*)alloc((size_t)M * FC * 2);
  unsigned short* X3   = (unsigned short*)alloc((size_t)M * FC * 2);
  float*          Y3   = (float*)alloc((size_t)4 * M * 96 * 4);
  float*          ps   = (float*)alloc((size_t)RG * FC * 4);
  float*          pq   = (float*)alloc((size_t)RG * FC * 4);
  float*          sc1  = (float*)alloc((size_t)FC * 4);
  float*          sh1  = (float*)alloc((size_t)FC * 4);
  float*          sc2  = (float*)alloc((size_t)FC * 4);
  float*          sh2  = (float*)alloc((size_t)FC * 4);

  // weight conversions (must redo each call — no cross-call state allowed)
  {
    size_t n4 = (size_t)FC * K1 / 4;
    cvt_bf16x4_kernel<<<(unsigned)((n4 + 255) / 256), 256, 0, stream>>>(
        (const float4*)fc1_w, (ushort4v*)W1b, n4);
  }
  {
    size_t n4 = (size_t)FC * FC / 4;
    cvt_bf16x4_kernel<<<(unsigned)((n4 + 255) / 256), 256, 0, stream>>>(
        (const float4*)fc2_w, (ushort4v*)W2b, n4);
  }
  cvt_pad_pred_kernel<<<(96 * 1024) / 256, 256, 0, stream>>>(pred_w, W3b);

  // ROI align (fused, W on-the-fly) -> X1 (2048 x 12544) bf16
  roi_mm2_kernel<<<dim3(2048, 8), 256, 0, stream>>>(feat_p3, feat_p4, feat_p5,
                                                    bbox2d, anchor_id, X1);

  // fc1: X1 (2048x12544) @ W1^T -> Yp (4 partials of 2048x1024)
  gemm_bt_swz<4><<<dim3(M / 128, FC / 128, 4), 256, 0, stream>>>(X1, W1b, Yp, M, FC, K1);

  // BN1: reduce partials + stats (512 blocks), finalize, apply+ReLU -> X2 bf16
  bn_stats_red_kernel<<<dim3(FC / 256, RG), 256, 0, stream>>>(Yp, Yr, ps, pq, FC, M / RG, 4, (size_t)M * FC);
  bn_finalize_kernel<<<FC / 256, 256, 0, stream>>>(ps, pq, bn1_g, bn1_b, sc1, sh1, FC, RG, 1.0f / M);
  bn_apply4_kernel<<<(M * FC / 4) / 256, 256, 0, stream>>>(
      (const float4*)Yr, sc1, sh1, (ushort4v*)X2, FC / 4 - 1, M * FC / 4);

  // fc2: X2 @ W2^T -> Yp (2 partials)
  gemm_bt_swz<2><<<dim3(M / 128, FC / 128, 2), 256, 0, stream>>>(X2, W2b, Yp, M, FC, FC);

  // BN2 + ReLU -> X3 bf16
  bn_stats_red_kernel<<<dim3(FC / 256, RG), 256, 0, stream>>>(Yp, Yr, ps, pq, FC, M / RG, 2, (size_t)M * FC);
  bn_finalize_kernel<<<FC / 256, 256, 0, stream>>>(ps, pq, bn2_g, bn2_b, sc2, sh2, FC, RG, 1.0f / M);
  bn_apply4_kernel<<<(M * FC / 4) / 256, 256, 0, stream>>>(
      (const float4*)Yr, sc2, sh2, (ushort4v*)X3, FC / 4 - 1, M * FC / 4);

  // pred head: X3 @ W3p^T -> Y3 (split-K=4 partials of 2048 x 96)
  gemm_bt_kernel<64, 96, 2, 2, 4><<<dim3(M / 64, 1, 4), 256, 0, stream>>>(X3, W3b, Y3, M, 96, FC);

  // decode -> out (2048 x 94)
  decode_kernel<<<(2048 * 94 + 255) / 256, 256, 0, stream>>>(Y3, pred_b, anchors, anchor_id, out);
}